// Round 1
// baseline (1347.808 us; speedup 1.0000x reference)
//
#include <hip/hip_runtime.h>

#define TT 512
#define BB 1024
#define XD 24
#define ZD 16
#define HD 64

typedef __attribute__((ext_vector_type(8))) short bf16x8;
typedef __attribute__((ext_vector_type(4))) float f32x4;

#define MFMA(a, b, c) __builtin_amdgcn_mfma_f32_16x16x32_bf16((a), (b), (c), 0, 0, 0)

__device__ __forceinline__ unsigned short f2b(float f) {
    unsigned int x = __float_as_uint(f);
    x = (x + 0x7fffu + ((x >> 16) & 1u)) >> 16;   // RNE fp32 -> bf16
    return (unsigned short)x;
}

__device__ __forceinline__ float sigm(float x) {
    return 1.0f / (1.0f + __expf(-x));
}

__device__ __forceinline__ float tanh_fast(float x) {
    x = fminf(fmaxf(x, -30.0f), 30.0f);
    float e = __expf(2.0f * x);
    return (e - 1.0f) / (e + 1.0f);
}

__device__ __forceinline__ float softplus_f(float x) {
    return fmaxf(x, 0.0f) + log1pf(__expf(-fabsf(x)));
}

// ---- LDS activation buffers: [16 rows][64 cols] bf16, 128B row stride,
// ---- XOR-swizzled by ((row&7)<<4) so A-fragment ds_read_b128 is ~conflict-free.
__device__ __forceinline__ bf16x8 read_af(const unsigned short* buf, int ktile, int lane) {
    int row = lane & 15;
    int byteoff = (row * 128 + ktile * 64 + ((lane >> 4) << 4)) ^ ((row & 7) << 4);
    return *reinterpret_cast<const bf16x8*>(reinterpret_cast<const char*>(buf) + byteoff);
}

__device__ __forceinline__ void write_a16(unsigned short* buf, int row, int col, unsigned short v) {
    int byteoff = (row * 128 + col * 2) ^ ((row & 7) << 4);
    *reinterpret_cast<unsigned short*>(reinterpret_cast<char*>(buf) + byteoff) = v;
}

// D-frag (row=(l>>4)*4+q, col=l&15) -> bf16 LDS A-buffer, optional relu
__device__ __forceinline__ void write_dfrag(unsigned short* buf, f32x4 acc, int lane, int colbase, bool dorelu) {
    int col = colbase + (lane & 15);
#pragma unroll
    for (int q = 0; q < 4; q++) {
        int row = ((lane >> 4) << 2) + q;
        float v = acc[q];
        if (dorelu) v = fmaxf(v, 0.0f);
        write_a16(buf, row, col, f2b(v));
    }
}

// Load one B-fragment (16 cols x 32 k) of a row-major [K][ldn] fp32 weight matrix.
// Lane l holds W[k0 + (l>>4)*8 + j][n0 + (l&15)], zero-padded past Kreal.
__device__ __forceinline__ bf16x8 load_bf(const float* W, int ldn, int Kreal, int k0, int n0, int lane) {
    int col = n0 + (lane & 15);
    int kb = k0 + ((lane >> 4) << 3);
    bf16x8 r;
#pragma unroll
    for (int j = 0; j < 8; j++) {
        int k = kb + j;
        float v = (k < Kreal) ? W[(size_t)k * ldn + col] : 0.0f;
        r[j] = (short)f2b(v);
    }
    return r;
}

__global__ __launch_bounds__(256, 1) void vrnn_kernel(
    const float* __restrict__ src, const float* __restrict__ eps,
    const float* __restrict__ Wx1, const float* __restrict__ bx1,
    const float* __restrict__ Wx2, const float* __restrict__ bx2,
    const float* __restrict__ Wz,  const float* __restrict__ bz,
    const float* __restrict__ We1, const float* __restrict__ be1,
    const float* __restrict__ We2, const float* __restrict__ be2,
    const float* __restrict__ Wem, const float* __restrict__ bem,
    const float* __restrict__ Wes, const float* __restrict__ bes,
    const float* __restrict__ Wih, const float* __restrict__ Whh,
    const float* __restrict__ Wf1, const float* __restrict__ bf1,
    const float* __restrict__ Wf2, const float* __restrict__ bf2,
    const float* __restrict__ Wf3, const float* __restrict__ bf3,
    float* __restrict__ out)
{
    __shared__ unsigned short xA[16 * 64];
    __shared__ unsigned short hA[2][16 * 64];
    __shared__ unsigned short pxA[16 * 64];
    __shared__ unsigned short axA[16 * 64];
    __shared__ unsigned short a1A[16 * 64];
    __shared__ unsigned short enA[16 * 64];
    __shared__ unsigned short zA[16 * 64];
    __shared__ unsigned short pzA[16 * 64];
    __shared__ float epsF[16 * 16];
    __shared__ float pzF[16 * 64];
    __shared__ float o1F[16 * 64];
    __shared__ float o2F[16 * 32];

    const int tid = threadIdx.x;
    const int w = tid >> 6;
    const int lane = tid & 63;
    const int lcol = lane & 15;
    const int lgr = lane >> 4;
    const int r0 = blockIdx.x * 16;
    const int nw = w * 16;   // this wave's 16-col slice for 64-wide stages / per-gate slices

    // ---------------- weight fragments (held in VGPRs across all 512 steps) --------------
    bf16x8 wx1f = load_bf(Wx1, 64, 24, 0, nw, lane);
    bf16x8 wx2f0 = load_bf(Wx2, 64, 64, 0, nw, lane);
    bf16x8 wx2f1 = load_bf(Wx2, 64, 64, 32, nw, lane);
    bf16x8 we1f[4];
#pragma unroll
    for (int kt = 0; kt < 4; kt++) we1f[kt] = load_bf(We1, 64, 128, kt * 32, nw, lane);
    bf16x8 we2f0 = load_bf(We2, 64, 64, 0, nw, lane);
    bf16x8 we2f1 = load_bf(We2, 64, 64, 32, nw, lane);
    bf16x8 wemf0 = load_bf(Wem, 16, 64, 0, 0, lane);
    bf16x8 wemf1 = load_bf(Wem, 16, 64, 32, 0, lane);
    bf16x8 wesf0 = load_bf(Wes, 16, 64, 0, 0, lane);
    bf16x8 wesf1 = load_bf(Wes, 16, 64, 32, 0, lane);
    bf16x8 wzf = load_bf(Wz, 64, 16, 0, nw, lane);
    // gate-aligned slices: wave w owns cols [16w,16w+16) of each gate block (r,z,n)
    bf16x8 wihf[3][4];
    bf16x8 whhf[3][2];
#pragma unroll
    for (int g = 0; g < 3; g++) {
#pragma unroll
        for (int kt = 0; kt < 4; kt++) wihf[g][kt] = load_bf(Wih, 192, 128, kt * 32, g * 64 + nw, lane);
#pragma unroll
        for (int kt = 0; kt < 2; kt++) whhf[g][kt] = load_bf(Whh, 192, 64, kt * 32, g * 64 + nw, lane);
    }

    const float b_x1 = bx1[nw + lcol];
    const float b_x2 = bx2[nw + lcol];
    const float b_e1 = be1[nw + lcol];
    const float b_e2 = be2[nw + lcol];
    const float b_zz = bz[nw + lcol];
    const float b_m = bem[lcol];
    const float b_s = bes[lcol];

    // ---------------- LDS init (zero-padded cols of xA/zA; h0 = 0) ----------------------
    for (int i = tid; i < 16 * 64; i += 256) {
        xA[i] = 0;
        zA[i] = 0;
        hA[0][i] = 0;
    }
    float hreg[4] = {0.f, 0.f, 0.f, 0.f};

    // ---------------- x/eps prefetch setup ----------------------------------------------
    const int xv0 = tid;                       // 0..255 -> (row, col) of the 16x24 x tile
    const int xr_0 = xv0 / 24, xc_0 = xv0 % 24;
    const int xv1 = tid + 256;                 // 256..383 for tid<128
    const int xr_1 = xv1 / 24, xc_1 = xv1 % 24;
    const bool has1 = (xv1 < 384);
    const float* xp0 = src + (size_t)(r0 + xr_0) * TT * XD + xc_0;
    const float* xp1 = has1 ? (src + (size_t)(r0 + xr_1) * TT * XD + xc_1) : src;
    const int er_ = tid >> 4, ec_ = tid & 15;
    const float* ep = eps + (size_t)(r0 + er_) * TT * ZD + ec_;

    float fx0 = xp0[0];
    float fx1 = has1 ? xp1[0] : 0.0f;
    float fe = ep[0];

    int cur = 0;

    for (int t = 0; t < TT; t++) {
        // stage this step's x/eps into LDS, then issue next step's loads
        write_a16(xA, xr_0, xc_0, f2b(fx0));
        if (has1) write_a16(xA, xr_1, xc_1, f2b(fx1));
        epsF[tid] = fe;
        if (t + 1 < TT) {
            fx0 = xp0[(size_t)(t + 1) * XD];
            if (has1) fx1 = xp1[(size_t)(t + 1) * XD];
            fe = ep[(size_t)(t + 1) * ZD];
        }
        __syncthreads();   // (1) x/eps staged; prev-step h writes visible

        // s1: ax = relu(x @ Wx1 + bx1)
        f32x4 acc = (f32x4){b_x1, b_x1, b_x1, b_x1};
        acc = MFMA(read_af(xA, 0, lane), wx1f, acc);
        write_dfrag(axA, acc, lane, nw, true);
        __syncthreads();   // (2)

        // s2: phi_x = relu(ax @ Wx2 + bx2)
        acc = (f32x4){b_x2, b_x2, b_x2, b_x2};
        acc = MFMA(read_af(axA, 0, lane), wx2f0, acc);
        acc = MFMA(read_af(axA, 1, lane), wx2f1, acc);
        write_dfrag(pxA, acc, lane, nw, true);
        __syncthreads();   // (3)

        // s3: a1 = relu([phi_x | h] @ We1 + be1)
        acc = (f32x4){b_e1, b_e1, b_e1, b_e1};
        acc = MFMA(read_af(pxA, 0, lane), we1f[0], acc);
        acc = MFMA(read_af(pxA, 1, lane), we1f[1], acc);
        acc = MFMA(read_af(hA[cur], 0, lane), we1f[2], acc);
        acc = MFMA(read_af(hA[cur], 1, lane), we1f[3], acc);
        write_dfrag(a1A, acc, lane, nw, true);
        __syncthreads();   // (4)

        // s4: enc = relu(a1 @ We2 + be2)
        acc = (f32x4){b_e2, b_e2, b_e2, b_e2};
        acc = MFMA(read_af(a1A, 0, lane), we2f0, acc);
        acc = MFMA(read_af(a1A, 1, lane), we2f1, acc);
        write_dfrag(enA, acc, lane, nw, true);
        __syncthreads();   // (5)

        // s5: mean/std (all waves compute redundantly; wave 0 writes z)
        {
            f32x4 am = (f32x4){b_m, b_m, b_m, b_m};
            f32x4 as = (f32x4){b_s, b_s, b_s, b_s};
            bf16x8 e0 = read_af(enA, 0, lane);
            bf16x8 e1 = read_af(enA, 1, lane);
            am = MFMA(e0, wemf0, am);
            am = MFMA(e1, wemf1, am);
            as = MFMA(e0, wesf0, as);
            as = MFMA(e1, wesf1, as);
            if (w == 0) {
#pragma unroll
                for (int q = 0; q < 4; q++) {
                    int row = (lgr << 2) + q;
                    float sd = softplus_f(as[q]);
                    float zq = epsF[row * 16 + lcol] * sd + am[q];
                    write_a16(zA, row, lcol, f2b(zq));
                }
            }
        }
        __syncthreads();   // (6)

        // s6: phi_z = relu(z @ Wz + bz)
        acc = (f32x4){b_zz, b_zz, b_zz, b_zz};
        acc = MFMA(read_af(zA, 0, lane), wzf, acc);
        write_dfrag(pzA, acc, lane, nw, true);
        if (t == TT - 1) {
#pragma unroll
            for (int q = 0; q < 4; q++) {
                int row = (lgr << 2) + q;
                pzF[row * 64 + nw + lcol] = fmaxf(acc[q], 0.0f);
            }
        }
        __syncthreads();   // (7)

        // s7: GRU gates.  gi = [phi_x|phi_z] @ Wih ; gh = h @ Whh  (bias-free)
        {
            bf16x8 ax0 = read_af(pxA, 0, lane);
            bf16x8 ax1 = read_af(pxA, 1, lane);
            bf16x8 az0 = read_af(pzA, 0, lane);
            bf16x8 az1 = read_af(pzA, 1, lane);
            bf16x8 ah0 = read_af(hA[cur], 0, lane);
            bf16x8 ah1 = read_af(hA[cur], 1, lane);

            f32x4 gir = (f32x4){0.f, 0.f, 0.f, 0.f};
            f32x4 giz = gir, gin = gir, ghr = gir, ghz = gir, ghn = gir;

            gir = MFMA(ax0, wihf[0][0], gir); gir = MFMA(ax1, wihf[0][1], gir);
            gir = MFMA(az0, wihf[0][2], gir); gir = MFMA(az1, wihf[0][3], gir);
            giz = MFMA(ax0, wihf[1][0], giz); giz = MFMA(ax1, wihf[1][1], giz);
            giz = MFMA(az0, wihf[1][2], giz); giz = MFMA(az1, wihf[1][3], giz);
            gin = MFMA(ax0, wihf[2][0], gin); gin = MFMA(ax1, wihf[2][1], gin);
            gin = MFMA(az0, wihf[2][2], gin); gin = MFMA(az1, wihf[2][3], gin);
            ghr = MFMA(ah0, whhf[0][0], ghr); ghr = MFMA(ah1, whhf[0][1], ghr);
            ghz = MFMA(ah0, whhf[1][0], ghz); ghz = MFMA(ah1, whhf[1][1], ghz);
            ghn = MFMA(ah0, whhf[2][0], ghn); ghn = MFMA(ah1, whhf[2][1], ghn);

            int nxt = cur ^ 1;
#pragma unroll
            for (int q = 0; q < 4; q++) {
                int row = (lgr << 2) + q;
                float rg = sigm(gir[q] + ghr[q]);
                float ug = sigm(giz[q] + ghz[q]);
                float ng = tanh_fast(gin[q] + rg * ghn[q]);
                float hn = (1.0f - ug) * ng + ug * hreg[q];
                hreg[q] = hn;
                write_a16(hA[nxt], row, nw + lcol, f2b(hn));
            }
            cur = nxt;
        }
        // next loop-top barrier (1) makes hA[nxt] visible before reads
    }
    __syncthreads();

    // ---------------- regressor head on last-step phi_z (fp32, scalar) ------------------
    {
        int r = tid >> 4, c0 = (tid & 15) * 4;
        float s0 = bf1[c0], s1 = bf1[c0 + 1], s2 = bf1[c0 + 2], s3 = bf1[c0 + 3];
        for (int k = 0; k < 64; k++) {
            float p = pzF[r * 64 + k];
            const float* wr = Wf1 + (size_t)k * 64 + c0;
            s0 += p * wr[0]; s1 += p * wr[1]; s2 += p * wr[2]; s3 += p * wr[3];
        }
        o1F[r * 64 + c0 + 0] = fmaxf(s0, 0.f);
        o1F[r * 64 + c0 + 1] = fmaxf(s1, 0.f);
        o1F[r * 64 + c0 + 2] = fmaxf(s2, 0.f);
        o1F[r * 64 + c0 + 3] = fmaxf(s3, 0.f);
    }
    __syncthreads();
    {
        int r = tid >> 4, c0 = (tid & 15) * 2;
        float s0 = bf2[c0], s1 = bf2[c0 + 1];
        for (int k = 0; k < 64; k++) {
            float p = o1F[r * 64 + k];
            s0 += p * Wf2[(size_t)k * 32 + c0];
            s1 += p * Wf2[(size_t)k * 32 + c0 + 1];
        }
        o2F[r * 32 + c0] = fmaxf(s0, 0.f);
        o2F[r * 32 + c0 + 1] = fmaxf(s1, 0.f);
    }
    __syncthreads();
    if (tid < 16) {
        float s = bf3[0];
        for (int k = 0; k < 32; k++) s += o2F[tid * 32 + k] * Wf3[k];
        out[r0 + tid] = s;
    }
    // phi_z output: out[BB + b*64 + c]
#pragma unroll
    for (int i = 0; i < 4; i++) {
        int v = tid * 4 + i;
        int rr = v >> 6, cc = v & 63;
        out[BB + (size_t)(r0 + rr) * 64 + cc] = pzF[rr * 64 + cc];
    }
}

extern "C" void kernel_launch(void* const* d_in, const int* in_sizes, int n_in,
                              void* d_out, int out_size, void* d_ws, size_t ws_size,
                              hipStream_t stream) {
    (void)in_sizes; (void)n_in; (void)d_ws; (void)ws_size; (void)out_size;
    const float* src = (const float*)d_in[0];
    const float* eps = (const float*)d_in[1];
    const float* Wx1 = (const float*)d_in[2];
    const float* bx1 = (const float*)d_in[3];
    const float* Wx2 = (const float*)d_in[4];
    const float* bx2 = (const float*)d_in[5];
    const float* Wz  = (const float*)d_in[6];
    const float* bz  = (const float*)d_in[7];
    const float* We1 = (const float*)d_in[8];
    const float* be1 = (const float*)d_in[9];
    const float* We2 = (const float*)d_in[10];
    const float* be2 = (const float*)d_in[11];
    const float* Wem = (const float*)d_in[12];
    const float* bem = (const float*)d_in[13];
    const float* Wes = (const float*)d_in[14];
    const float* bes = (const float*)d_in[15];
    const float* Wih = (const float*)d_in[16];
    const float* Whh = (const float*)d_in[17];
    const float* Wf1 = (const float*)d_in[18];
    const float* bf1 = (const float*)d_in[19];
    const float* Wf2 = (const float*)d_in[20];
    const float* bf2 = (const float*)d_in[21];
    const float* Wf3 = (const float*)d_in[22];
    const float* bf3 = (const float*)d_in[23];
    float* out = (float*)d_out;

    hipLaunchKernelGGL(vrnn_kernel, dim3(BB / 16), dim3(256), 0, stream,
                       src, eps, Wx1, bx1, Wx2, bx2, Wz, bz, We1, be1, We2, be2,
                       Wem, bem, Wes, bes, Wih, Whh, Wf1, bf1, Wf2, bf2, Wf3, bf3, out);
}